// Round 1
// baseline (1240.927 us; speedup 1.0000x reference)
//
#include <hip/hip_runtime.h>
#include <hip/hip_bf16.h>
#include <stdint.h>

// Problem constants (QKVParallelLinearWithLoRA)
#define S_TOK 16384
#define DIN   4096
#define OUTQ  4096
#define OUTKV 1024
#define NOUT  6144   // OUTQ + 2*OUTKV
#define LRANK 64

typedef __attribute__((ext_vector_type(8))) short bf16x8;           // 8 bf16 = 4 VGPR
typedef __attribute__((ext_vector_type(4))) float f32x4;            // MFMA acc frag
typedef __attribute__((ext_vector_type(4))) unsigned short u16x4;   // 4 bf16 store

static __device__ __forceinline__ unsigned short f2bf(float f) {
  // round-to-nearest-even fp32 -> bf16
  uint32_t u = __float_as_uint(f);
  u += 0x7FFFu + ((u >> 16) & 1u);
  return (unsigned short)(u >> 16);
}

static __device__ __forceinline__ void gload_lds16(const void* g, void* l) {
  // async global->LDS, 16B per lane; LDS dest must be wave-uniform base (+lane*16)
  __builtin_amdgcn_global_load_lds((const __attribute__((address_space(1))) void*)g,
                                   (__attribute__((address_space(3))) void*)l,
                                   16, 0, 0);
}

// ---------------------------------------------------------------------------
// Kernel 1: x fp32 -> bf16 (vectorized float4 -> 4x u16)
// ---------------------------------------------------------------------------
__global__ __launch_bounds__(256) void cvt_f32_bf16(const float* __restrict__ in,
                                                    unsigned short* __restrict__ out,
                                                    int n4) {
  int i = blockIdx.x * blockDim.x + threadIdx.x;
  const int stride = gridDim.x * blockDim.x;
  const float4* in4 = (const float4*)in;
  for (; i < n4; i += stride) {
    float4 v = in4[i];
    u16x4 o;
    o.x = f2bf(v.x); o.y = f2bf(v.y); o.z = f2bf(v.z); o.w = f2bf(v.w);
    *(u16x4*)(out + (size_t)i * 4) = o;
  }
}

// ---------------------------------------------------------------------------
// Kernel 2: W_eff[o][d] = W[o][d] + sum_r B_seg[o'][r] * A[seg*64+r][d] -> bf16
// tile: 64 o x 128 d per block (256 threads). LDS: A-tile 32KB + B-tile 16KB.
// segment boundaries (4096, 5120) are multiples of 64, so no tile straddles.
// ---------------------------------------------------------------------------
__global__ __launch_bounds__(256) void prep_weff(const float* __restrict__ W,
                                                 const float* __restrict__ A,
                                                 const float* __restrict__ Bq,
                                                 const float* __restrict__ Bk,
                                                 const float* __restrict__ Bv,
                                                 unsigned short* __restrict__ Weff) {
  __shared__ float As_[64][128];
  __shared__ float Bs_[64][64];
  const int o0 = blockIdx.x * 64;
  const int d0 = blockIdx.y * 128;
  const int t = threadIdx.x;

  const float* Bseg; int seg, ob;
  if (o0 < OUTQ)              { seg = 0; Bseg = Bq; ob = o0; }
  else if (o0 < OUTQ + OUTKV) { seg = 1; Bseg = Bk; ob = o0 - OUTQ; }
  else                        { seg = 2; Bseg = Bv; ob = o0 - OUTQ - OUTKV; }

  { // stage B rows [ob, ob+64) x 64 : contiguous 16KB
    const float4* src = (const float4*)(Bseg + (size_t)ob * LRANK);
    float4* dst = (float4*)&Bs_[0][0];
    for (int i = t; i < 64 * 64 / 4; i += 256) dst[i] = src[i];
  }
  // stage A rows [seg*64, +64) cols [d0, d0+128)
  for (int i = t; i < 64 * 32; i += 256) {
    int r = i >> 5, c4 = i & 31;
    *(float4*)&As_[r][c4 * 4] =
        *(const float4*)(A + (size_t)(seg * 64 + r) * DIN + d0 + c4 * 4);
  }
  __syncthreads();

  const int tx = t & 31;   // d-quad (float4 column)
  const int tg = t >> 5;   // o-group: rows tg*8 .. +8
  for (int oi = tg * 8; oi < tg * 8 + 8; ++oi) {
    const int o = o0 + oi;
    float4 acc = *(const float4*)(W + (size_t)o * DIN + d0 + tx * 4);
#pragma unroll 8
    for (int r = 0; r < 64; ++r) {
      const float b = Bs_[oi][r];            // wave-broadcast
      const float4 a = *(const float4*)&As_[r][tx * 4];
      acc.x += b * a.x; acc.y += b * a.y; acc.z += b * a.z; acc.w += b * a.w;
    }
    u16x4 ov;
    ov.x = f2bf(acc.x); ov.y = f2bf(acc.y); ov.z = f2bf(acc.z); ov.w = f2bf(acc.w);
    *(u16x4*)(Weff + (size_t)o * DIN + d0 + tx * 4) = ov;
  }
}

// ---------------------------------------------------------------------------
// Kernel 3: C[m,n] = sum_k Xb[m,k]*Wb[n,k] + bias[n]   (bf16 MFMA, fp32 out)
// m97 structure: 128x128 tile, BK=32, 4 waves (each a 64x64 sub-tile, 4x4
// frags of 16x16x32), global_load_lds width-16 staging, 2 barriers / K-step.
// ---------------------------------------------------------------------------
__global__ __launch_bounds__(256) void gemm_bt_bias(const unsigned short* __restrict__ Xb,
                                                    const unsigned short* __restrict__ Wb,
                                                    const float* __restrict__ bias,
                                                    float* __restrict__ C) {
  __shared__ unsigned short As[128 * 32];  // 8KB, row-major [row][32]
  __shared__ unsigned short Bs[128 * 32];  // 8KB

  const int bid = blockIdx.x;
  const int nwg = 6144;                 // grid size; % 8 == 0 -> simple swizzle OK
  const int cpx = nwg / 8;
  const int swz = (bid & 7) * cpx + (bid >> 3);
  const int mt = swz & 127;             // m-tile fast-varying: W panel L2-resident
  const int nt = swz >> 7;
  const int m0 = mt * 128;
  const int n0 = nt * 128;

  const int t = threadIdx.x;
  const int lane = t & 63;
  const int w = t >> 6;
  const int wm = (w >> 1) * 64;         // wave sub-tile origin in block tile
  const int wn = (w & 1) * 64;

  f32x4 acc[4][4];
#pragma unroll
  for (int i = 0; i < 4; ++i)
#pragma unroll
    for (int j = 0; j < 4; ++j)
      acc[i][j] = f32x4{0.f, 0.f, 0.f, 0.f};

  // staging: 8 chunks of 1KB each for A and B; wave w takes chunks {w, w+4}.
  // within a chunk: lane covers row = c*16 + lane/4, k-off = (lane%4)*8
  const int srow = lane >> 2;
  const int skof = (lane & 3) * 8;
  const int c0 = w, c1 = w + 4;
  const size_t a_base0 = (size_t)(m0 + c0 * 16 + srow) * DIN + skof;
  const size_t a_base1 = (size_t)(m0 + c1 * 16 + srow) * DIN + skof;
  const size_t b_base0 = (size_t)(n0 + c0 * 16 + srow) * DIN + skof;
  const size_t b_base1 = (size_t)(n0 + c1 * 16 + srow) * DIN + skof;

  // fragment read offsets (elements): A row = wm + mi*16 + (lane&15), k-slice (lane>>4)*8
  const int afrag0 = (wm + (lane & 15)) * 32 + (lane >> 4) * 8;
  const int bfrag0 = (wn + (lane & 15)) * 32 + (lane >> 4) * 8;

  for (int k0 = 0; k0 < DIN; k0 += 32) {
    __syncthreads();  // previous compute done before overwrite
    gload_lds16(Xb + a_base0 + k0, &As[c0 * 512]);
    gload_lds16(Xb + a_base1 + k0, &As[c1 * 512]);
    gload_lds16(Wb + b_base0 + k0, &Bs[c0 * 512]);
    gload_lds16(Wb + b_base1 + k0, &Bs[c1 * 512]);
    __syncthreads();  // compiler drains vmcnt before barrier -> tiles visible

    bf16x8 af[4], bf[4];
#pragma unroll
    for (int i = 0; i < 4; ++i) {
      af[i] = *(const bf16x8*)&As[afrag0 + i * 16 * 32];
      bf[i] = *(const bf16x8*)&Bs[bfrag0 + i * 16 * 32];
    }
#pragma unroll
    for (int mi = 0; mi < 4; ++mi)
#pragma unroll
      for (int ni = 0; ni < 4; ++ni)
        acc[mi][ni] = __builtin_amdgcn_mfma_f32_16x16x32_bf16(af[mi], bf[ni],
                                                              acc[mi][ni], 0, 0, 0);
  }

  // epilogue: C/D layout col=lane&15, row=(lane>>4)*4+reg  (m89/m91-verified)
  const int cr = lane >> 4;
  const int cc = lane & 15;
#pragma unroll
  for (int ni = 0; ni < 4; ++ni) {
    const int col = n0 + wn + ni * 16 + cc;
    const float bv = bias[col];
#pragma unroll
    for (int mi = 0; mi < 4; ++mi) {
      const int row = m0 + wm + mi * 16 + cr * 4;
      f32x4 v = acc[mi][ni];
#pragma unroll
      for (int j = 0; j < 4; ++j)
        C[(size_t)(row + j) * NOUT + col] = v[j] + bv;
    }
  }
}

// ---------------------------------------------------------------------------
extern "C" void kernel_launch(void* const* d_in, const int* in_sizes, int n_in,
                              void* d_out, int out_size, void* d_ws, size_t ws_size,
                              hipStream_t stream) {
  const float* x    = (const float*)d_in[0];
  const float* Wqkv = (const float*)d_in[1];
  const float* bias = (const float*)d_in[2];
  const float* Aq   = (const float*)d_in[3];
  const float* Bq   = (const float*)d_in[4];
  const float* Bk   = (const float*)d_in[5];
  const float* Bv   = (const float*)d_in[6];
  float* out = (float*)d_out;

  // workspace layout: x_bf16 (128MB) | W_eff_bf16 (48MB)  -> 184.5MB total
  unsigned short* xb = (unsigned short*)d_ws;
  unsigned short* wb = xb + (size_t)S_TOK * DIN;

  cvt_f32_bf16<<<2048, 256, 0, stream>>>(x, xb, S_TOK * DIN / 4);

  dim3 g1(NOUT / 64, DIN / 128);
  prep_weff<<<g1, 256, 0, stream>>>(Wqkv, Aq, Bq, Bk, Bv, wb);

  gemm_bt_bias<<<6144, 256, 0, stream>>>(xb, wb, bias, out);
}

// Round 2
// 1225.799 us; speedup vs baseline: 1.0123x; 1.0123x over previous
//
#include <hip/hip_runtime.h>
#include <hip/hip_bf16.h>
#include <stdint.h>

// Problem constants (QKVParallelLinearWithLoRA)
#define S_TOK 16384
#define DIN   4096
#define OUTQ  4096
#define OUTKV 1024
#define NOUT  6144   // OUTQ + 2*OUTKV
#define LRANK 64

typedef __attribute__((ext_vector_type(8))) short bf16x8;           // 8 bf16 = 4 VGPR
typedef __attribute__((ext_vector_type(4))) float f32x4;            // MFMA acc frag
typedef __attribute__((ext_vector_type(4))) unsigned short u16x4;   // 4 bf16 store

static __device__ __forceinline__ unsigned short f2bf(float f) {
  uint32_t u = __float_as_uint(f);
  u += 0x7FFFu + ((u >> 16) & 1u);
  return (unsigned short)(u >> 16);
}

static __device__ __forceinline__ void gload_lds16(const void* g, void* l) {
  __builtin_amdgcn_global_load_lds((const __attribute__((address_space(1))) void*)g,
                                   (__attribute__((address_space(3))) void*)l,
                                   16, 0, 0);
}

// ---------------------------------------------------------------------------
// Kernel 1: x fp32 -> bf16
// ---------------------------------------------------------------------------
__global__ __launch_bounds__(256) void cvt_f32_bf16(const float* __restrict__ in,
                                                    unsigned short* __restrict__ out,
                                                    int n4) {
  int i = blockIdx.x * blockDim.x + threadIdx.x;
  const int stride = gridDim.x * blockDim.x;
  const float4* in4 = (const float4*)in;
  for (; i < n4; i += stride) {
    float4 v = in4[i];
    u16x4 o;
    o.x = f2bf(v.x); o.y = f2bf(v.y); o.z = f2bf(v.z); o.w = f2bf(v.w);
    *(u16x4*)(out + (size_t)i * 4) = o;
  }
}

// ---------------------------------------------------------------------------
// Kernel 2: W_eff[o][d] = W[o][d] + sum_r B_seg[o'][r] * A[seg*64+r][d] -> bf16
// ---------------------------------------------------------------------------
__global__ __launch_bounds__(256) void prep_weff(const float* __restrict__ W,
                                                 const float* __restrict__ A,
                                                 const float* __restrict__ Bq,
                                                 const float* __restrict__ Bk,
                                                 const float* __restrict__ Bv,
                                                 unsigned short* __restrict__ Weff) {
  __shared__ float As_[64][128];
  __shared__ float Bs_[64][64];
  const int o0 = blockIdx.x * 64;
  const int d0 = blockIdx.y * 128;
  const int t = threadIdx.x;

  const float* Bseg; int seg, ob;
  if (o0 < OUTQ)              { seg = 0; Bseg = Bq; ob = o0; }
  else if (o0 < OUTQ + OUTKV) { seg = 1; Bseg = Bk; ob = o0 - OUTQ; }
  else                        { seg = 2; Bseg = Bv; ob = o0 - OUTQ - OUTKV; }

  {
    const float4* src = (const float4*)(Bseg + (size_t)ob * LRANK);
    float4* dst = (float4*)&Bs_[0][0];
    for (int i = t; i < 64 * 64 / 4; i += 256) dst[i] = src[i];
  }
  for (int i = t; i < 64 * 32; i += 256) {
    int r = i >> 5, c4 = i & 31;
    *(float4*)&As_[r][c4 * 4] =
        *(const float4*)(A + (size_t)(seg * 64 + r) * DIN + d0 + c4 * 4);
  }
  __syncthreads();

  const int tx = t & 31;
  const int tg = t >> 5;
  for (int oi = tg * 8; oi < tg * 8 + 8; ++oi) {
    const int o = o0 + oi;
    float4 acc = *(const float4*)(W + (size_t)o * DIN + d0 + tx * 4);
#pragma unroll 8
    for (int r = 0; r < 64; ++r) {
      const float b = Bs_[oi][r];
      const float4 a = *(const float4*)&As_[r][tx * 4];
      acc.x += b * a.x; acc.y += b * a.y; acc.z += b * a.z; acc.w += b * a.w;
    }
    u16x4 ov;
    ov.x = f2bf(acc.x); ov.y = f2bf(acc.y); ov.z = f2bf(acc.z); ov.w = f2bf(acc.w);
    *(u16x4*)(Weff + (size_t)o * DIN + d0 + tx * 4) = ov;
  }
}

// ---------------------------------------------------------------------------
// Kernel 3: deep-pipelined 256x256 GEMM, BK=32, ring-4 LDS, counted vmcnt.
//   C[m,n] = sum_k Xb[m,k]*Wb[n,k] + bias[n]
// 8 waves (2M x 4N), per-wave 128x64 out = 8x4 frags of 16x16x32 bf16 MFMA.
// LDS: Ab[4][256*32] + Bb[4][256*32] = 128 KiB; tile j in slot j&3; 3 tiles
// prefetched ahead; one raw s_barrier + s_waitcnt vmcnt(8) per K-iteration
// (loads stay in flight across barriers -- T4). Swizzle: involution
// b ^= ((b>>7)&3)<<4 on tile-local byte offsets, applied to the GLOBAL source
// during staging (linear global_load_lds dest) and to fragment reads (T2).
// ---------------------------------------------------------------------------
__global__ __launch_bounds__(512, 2) void gemm_bt_bias(const unsigned short* __restrict__ Xb,
                                                       const unsigned short* __restrict__ Wb,
                                                       const float* __restrict__ bias,
                                                       float* __restrict__ C) {
  __shared__ unsigned short Ab[4][8192];  // 4 slots x 16KB (256 rows x 32 k)
  __shared__ unsigned short Bb[4][8192];

  const int bid = blockIdx.x;
  const int cpx = 1536 / 8;               // 1536 wg % 8 == 0 -> simple swizzle OK
  const int swz = (bid & 7) * cpx + (bid >> 3);
  const int mt = swz % 64;                // m fast-varying: blocks on one XCD share W panel
  const int nt = swz / 64;
  const int m0 = mt * 256;
  const int n0 = nt * 256;

  const int t = threadIdx.x;
  const int lane = t & 63;
  const int w = t >> 6;
  const int wm = (w >> 2) * 128;          // wave row origin (2 waves in M)
  const int wn = (w & 3) * 64;            // wave col origin (4 waves in N)

  // ---- staging constants: thread t covers row = i*128 + t/4, 16B k-slot t%4.
  // swizzle preserves row; logical k-slot = (t&3) ^ ((row>>1)&3).
  const int trow = t >> 2;
  const int ksl = (t & 3) ^ ((trow >> 1) & 3);
  const size_t gA0 = (size_t)(m0 + trow) * DIN + ksl * 8;
  const size_t gA1 = (size_t)(m0 + 128 + trow) * DIN + ksl * 8;
  const size_t gB0 = (size_t)(n0 + trow) * DIN + ksl * 8;
  const size_t gB1 = (size_t)(n0 + 128 + trow) * DIN + ksl * 8;
  const int ldst = t * 8;                 // element offset: lane*16B, wave-linear

#define STAGE(kt) do {                                                        \
    const int k0_ = (kt) * 32; const int sl_ = (kt) & 3;                      \
    gload_lds16(Xb + gA0 + k0_, &Ab[sl_][ldst]);                              \
    gload_lds16(Xb + gA1 + k0_, &Ab[sl_][4096 + ldst]);                       \
    gload_lds16(Wb + gB0 + k0_, &Bb[sl_][ldst]);                              \
    gload_lds16(Wb + gB1 + k0_, &Bb[sl_][4096 + ldst]);                       \
  } while (0)

  // ---- fragment read offsets (bytes): row = (wm|wn) + f*16 + (lane&15),
  // k-slice (lane>>4)*16B. XOR term reduces to ((lane&15)>>1)&3 (constant).
  const int lr = lane & 15;
  const int ks16 = (lane >> 4) * 16;
  const int fxor = (((lr >> 1) & 3) << 4);
  const int aoff = (((wm + lr) * 64 + ks16) ^ fxor);
  const int boff = (((wn + lr) * 64 + ks16) ^ fxor);

  f32x4 acc[8][4];
#pragma unroll
  for (int i = 0; i < 8; ++i)
#pragma unroll
    for (int j = 0; j < 4; ++j)
      acc[i][j] = f32x4{0.f, 0.f, 0.f, 0.f};

#define COMPUTE(j) do {                                                        \
    const char* Abase_ = (const char*)&Ab[(j) & 3][0];                         \
    const char* Bbase_ = (const char*)&Bb[(j) & 3][0];                         \
    bf16x8 af[8], bfr[4];                                                      \
    _Pragma("unroll")                                                          \
    for (int mi = 0; mi < 8; ++mi)                                             \
      af[mi] = *(const bf16x8*)(Abase_ + aoff + mi * 1024);                    \
    _Pragma("unroll")                                                          \
    for (int ni = 0; ni < 4; ++ni)                                             \
      bfr[ni] = *(const bf16x8*)(Bbase_ + boff + ni * 1024);                   \
    __builtin_amdgcn_s_setprio(1);                                             \
    _Pragma("unroll")                                                          \
    for (int mi = 0; mi < 8; ++mi)                                             \
      _Pragma("unroll")                                                        \
      for (int ni = 0; ni < 4; ++ni)                                           \
        acc[mi][ni] = __builtin_amdgcn_mfma_f32_16x16x32_bf16(af[mi], bfr[ni], \
                                                              acc[mi][ni], 0, 0, 0); \
    __builtin_amdgcn_s_setprio(0);                                             \
  } while (0)

  // prologue: 3 tiles in flight (12 loads)
  STAGE(0); STAGE(1); STAGE(2);

  // main loop: tiles 0..124, staging 3 ahead. vmcnt(8): own tile-j loads
  // (oldest 4 of 12) landed; barrier makes all waves' tile-j data visible and
  // fences the WAR on slot (j-1)&3 before STAGE(j+3) overwrites it.
  for (int j = 0; j < 125; ++j) {
    asm volatile("s_waitcnt vmcnt(8)\n\ts_barrier" ::: "memory");
    STAGE(j + 3);
    COMPUTE(j);
  }
  // epilogue: drain 8 -> 4 -> 0
  asm volatile("s_waitcnt vmcnt(8)\n\ts_barrier" ::: "memory");
  COMPUTE(125);
  asm volatile("s_waitcnt vmcnt(4)\n\ts_barrier" ::: "memory");
  COMPUTE(126);
  asm volatile("s_waitcnt vmcnt(0)\n\ts_barrier" ::: "memory");
  COMPUTE(127);

#undef STAGE
#undef COMPUTE

  // epilogue: C/D layout col=lane&15, row=(lane>>4)*4+reg (m89/m91-verified)
  const int cr4 = (lane >> 4) * 4;
#pragma unroll
  for (int ni = 0; ni < 4; ++ni) {
    const int col = n0 + wn + ni * 16 + lr;
    const float bv = bias[col];
#pragma unroll
    for (int mi = 0; mi < 8; ++mi) {
      const int row = m0 + wm + mi * 16 + cr4;
#pragma unroll
      for (int jj = 0; jj < 4; ++jj)
        C[(size_t)(row + jj) * NOUT + col] = acc[mi][ni][jj] + bv;
    }
  }
}

// ---------------------------------------------------------------------------
extern "C" void kernel_launch(void* const* d_in, const int* in_sizes, int n_in,
                              void* d_out, int out_size, void* d_ws, size_t ws_size,
                              hipStream_t stream) {
  const float* x    = (const float*)d_in[0];
  const float* Wqkv = (const float*)d_in[1];
  const float* bias = (const float*)d_in[2];
  const float* Aq   = (const float*)d_in[3];
  const float* Bq   = (const float*)d_in[4];
  const float* Bk   = (const float*)d_in[5];
  const float* Bv   = (const float*)d_in[6];
  float* out = (float*)d_out;

  unsigned short* xb = (unsigned short*)d_ws;                 // 128 MB
  unsigned short* wb = xb + (size_t)S_TOK * DIN;              // 48 MB

  cvt_f32_bf16<<<2048, 256, 0, stream>>>(x, xb, S_TOK * DIN / 4);

  dim3 g1(NOUT / 64, DIN / 128);
  prep_weff<<<g1, 256, 0, stream>>>(Wqkv, Aq, Bq, Bk, Bv, wb);

  gemm_bt_bias<<<1536, 512, 0, stream>>>(xb, wb, bias, out);
}

// Round 3
// 1016.509 us; speedup vs baseline: 1.2208x; 1.2059x over previous
//
#include <hip/hip_runtime.h>
#include <hip/hip_bf16.h>
#include <stdint.h>

// Problem constants (QKVParallelLinearWithLoRA)
#define S_TOK 16384
#define DIN   4096
#define OUTQ  4096
#define OUTKV 1024
#define NOUT  6144   // OUTQ + 2*OUTKV
#define LRANK 64

typedef __attribute__((ext_vector_type(8))) short bf16x8;           // 8 bf16 = 4 VGPR
typedef __attribute__((ext_vector_type(4))) float f32x4;            // MFMA acc frag
typedef __attribute__((ext_vector_type(4))) unsigned short u16x4;   // 4 bf16 store

static __device__ __forceinline__ unsigned short f2bf(float f) {
  uint32_t u = __float_as_uint(f);
  u += 0x7FFFu + ((u >> 16) & 1u);
  return (unsigned short)(u >> 16);
}

static __device__ __forceinline__ void gload_lds16(const void* g, void* l) {
  __builtin_amdgcn_global_load_lds((const __attribute__((address_space(1))) void*)g,
                                   (__attribute__((address_space(3))) void*)l,
                                   16, 0, 0);
}

// ---------------------------------------------------------------------------
// Kernel 1: x fp32 -> bf16
// ---------------------------------------------------------------------------
__global__ __launch_bounds__(256) void cvt_f32_bf16(const float* __restrict__ in,
                                                    unsigned short* __restrict__ out,
                                                    int n4) {
  int i = blockIdx.x * blockDim.x + threadIdx.x;
  const int stride = gridDim.x * blockDim.x;
  const float4* in4 = (const float4*)in;
  for (; i < n4; i += stride) {
    float4 v = in4[i];
    u16x4 o;
    o.x = f2bf(v.x); o.y = f2bf(v.y); o.z = f2bf(v.z); o.w = f2bf(v.w);
    *(u16x4*)(out + (size_t)i * 4) = o;
  }
}

// ---------------------------------------------------------------------------
// Kernel 2: W_eff[o][d] = W[o][d] + sum_r B_seg[o'][r] * A[seg*64+r][d] -> bf16
// ---------------------------------------------------------------------------
__global__ __launch_bounds__(256) void prep_weff(const float* __restrict__ W,
                                                 const float* __restrict__ A,
                                                 const float* __restrict__ Bq,
                                                 const float* __restrict__ Bk,
                                                 const float* __restrict__ Bv,
                                                 unsigned short* __restrict__ Weff) {
  __shared__ float As_[64][128];
  __shared__ float Bs_[64][64];
  const int o0 = blockIdx.x * 64;
  const int d0 = blockIdx.y * 128;
  const int t = threadIdx.x;

  const float* Bseg; int seg, ob;
  if (o0 < OUTQ)              { seg = 0; Bseg = Bq; ob = o0; }
  else if (o0 < OUTQ + OUTKV) { seg = 1; Bseg = Bk; ob = o0 - OUTQ; }
  else                        { seg = 2; Bseg = Bv; ob = o0 - OUTQ - OUTKV; }

  {
    const float4* src = (const float4*)(Bseg + (size_t)ob * LRANK);
    float4* dst = (float4*)&Bs_[0][0];
    for (int i = t; i < 64 * 64 / 4; i += 256) dst[i] = src[i];
  }
  for (int i = t; i < 64 * 32; i += 256) {
    int r = i >> 5, c4 = i & 31;
    *(float4*)&As_[r][c4 * 4] =
        *(const float4*)(A + (size_t)(seg * 64 + r) * DIN + d0 + c4 * 4);
  }
  __syncthreads();

  const int tx = t & 31;
  const int tg = t >> 5;
  for (int oi = tg * 8; oi < tg * 8 + 8; ++oi) {
    const int o = o0 + oi;
    float4 acc = *(const float4*)(W + (size_t)o * DIN + d0 + tx * 4);
#pragma unroll 8
    for (int r = 0; r < 64; ++r) {
      const float b = Bs_[oi][r];
      const float4 a = *(const float4*)&As_[r][tx * 4];
      acc.x += b * a.x; acc.y += b * a.y; acc.z += b * a.z; acc.w += b * a.w;
    }
    u16x4 ov;
    ov.x = f2bf(acc.x); ov.y = f2bf(acc.y); ov.z = f2bf(acc.z); ov.w = f2bf(acc.w);
    *(u16x4*)(Weff + (size_t)o * DIN + d0 + tx * 4) = ov;
  }
}

// ---------------------------------------------------------------------------
// Kernel 3: 256x256 GEMM, BK=64, 8-phase schedule (T1+T2+T3+T4+T5).
//   C[m,n] = sum_k Xb[m,k]*Wb[n,k] + bias[n]
// 8 waves (2M x 4N), per-wave 128x64 out = 8x4 frags of 16x16x32 bf16 MFMA.
// LDS: A/B x 2 bufs x 2 k-halves x (256 rows x 32 k) = 128 KiB.
// K-tile T (64 wide) lives in buf T&1. Iteration i: phases 1-4 compute tile
// 2i (buf0) while staging tile 2i+1 (buf1) half-by-half {A-k0,B-k0,A-k1,B-k1};
// phases 5-8 compute tile 2i+1 while staging tile 2i+2 (buf0).
// Phase (ks,fh): ds_read A-frags mi=fh*4..+3 (and B-frags if fh==0, reused
// for fh==1) at k-slice ks; issue one half-tile stage (2 gloads); barrier;
// lgkmcnt(0); setprio(1); 16 MFMA; setprio(0); [vmcnt(4) at even phases];
// barrier. vmcnt ledger (steady state): 8 loads outstanding at every even-
// phase end, oldest 4 are the half-tiles the next 2 phases read -> vmcnt(4),
// never 0 in main loop. Final iteration peeled: drains 4 -> 4 -> 0.
// Swizzle (T2): within each 8KB region, byte ^= ((row>>1)&3)<<4, applied to
// the GLOBAL source during staging (linear gload_lds dest, rule #21) and to
// fragment reads (fxor reduces to a per-lane constant). R2-verified: 0 confl.
// ---------------------------------------------------------------------------
__global__ __launch_bounds__(512, 1) void gemm_bt_bias(const unsigned short* __restrict__ Xb,
                                                       const unsigned short* __restrict__ Wb,
                                                       const float* __restrict__ bias,
                                                       float* __restrict__ C) {
  __shared__ unsigned short Alds[32768];  // [buf][kh][256 rows][32 k] = 4x16KB
  __shared__ unsigned short Blds[32768];

  const int bid = blockIdx.x;
  const int cpx = 1536 / 8;               // 1536 % 8 == 0 -> simple XCD swizzle OK
  const int swz = (bid & 7) * cpx + (bid >> 3);
  const int mt = swz % 64;                // m fast-varying: XCD-neighbors share W panel
  const int nt = swz / 64;
  const int m0 = mt * 256;
  const int n0 = nt * 256;

  const int t = threadIdx.x;
  const int lane = t & 63;
  const int w = t >> 6;
  const int wm = (w >> 2) * 128;          // 2 waves in M
  const int wn = (w & 3) * 64;            // 4 waves in N

  // ---- staging: thread t covers region row trow (+128 for 2nd gload),
  // phys 16B-slot t&3; logical k-slot = (t&3)^((trow>>1)&3) (inverse swizzle
  // applied to global source; LDS dest stays linear).
  const int trow = t >> 2;
  const int ksl = (t & 3) ^ ((trow >> 1) & 3);
  const size_t gA0 = (size_t)(m0 + trow) * DIN + ksl * 8;
  const size_t gA1 = (size_t)(m0 + 128 + trow) * DIN + ksl * 8;
  const size_t gB0 = (size_t)(n0 + trow) * DIN + ksl * 8;
  const size_t gB1 = (size_t)(n0 + 128 + trow) * DIN + ksl * 8;
  const int ldst = t * 8;                 // element offset within region

#define STAGE_A(T, kh) do {                                                   \
    const int rb_ = (((T) & 1) * 2 + (kh)) * 8192;                            \
    const size_t ko_ = (size_t)((T) * 64 + (kh) * 32);                        \
    gload_lds16(Xb + gA0 + ko_, &Alds[rb_ + ldst]);                           \
    gload_lds16(Xb + gA1 + ko_, &Alds[rb_ + 4096 + ldst]);                    \
  } while (0)
#define STAGE_B(T, kh) do {                                                   \
    const int rb_ = (((T) & 1) * 2 + (kh)) * 8192;                            \
    const size_t ko_ = (size_t)((T) * 64 + (kh) * 32);                        \
    gload_lds16(Wb + gB0 + ko_, &Blds[rb_ + ldst]);                           \
    gload_lds16(Wb + gB1 + ko_, &Blds[rb_ + 4096 + ldst]);                    \
  } while (0)

  // ---- fragment read offsets (bytes within region): row = base + lr,
  // 16B at (lane>>4)*16, swizzle-xor reduces to per-lane constant.
  const int lr = lane & 15;
  const int ks16 = (lane >> 4) * 16;
  const int fxor = ((lr >> 1) & 3) << 4;
  const int aoff = ((wm + lr) * 64 + ks16) ^ fxor;
  const int boff = ((wn + lr) * 64 + ks16) ^ fxor;

  f32x4 acc[8][4];
#pragma unroll
  for (int i = 0; i < 8; ++i)
#pragma unroll
    for (int j = 0; j < 4; ++j)
      acc[i][j] = f32x4{0.f, 0.f, 0.f, 0.f};
  bf16x8 bq[4];

#define END_P()  __builtin_amdgcn_s_barrier()
#define END_V4() do { asm volatile("s_waitcnt vmcnt(4)" ::: "memory");        \
                      __builtin_amdgcn_s_barrier(); } while (0)
#define END_V0() do { asm volatile("s_waitcnt vmcnt(0)" ::: "memory");        \
                      __builtin_amdgcn_s_barrier(); } while (0)

  // PH(buf, ks, fh, STAGE_STMT, ENDM): one phase.
#define PH(buf, ks, fh, STAGE_STMT, ENDM) do {                                \
    const char* Ar_ = (const char*)&Alds[((buf) * 2 + (ks)) * 8192];          \
    const char* Br_ = (const char*)&Blds[((buf) * 2 + (ks)) * 8192];          \
    bf16x8 af_[4];                                                            \
    if ((fh) == 0) {                                                          \
      _Pragma("unroll")                                                       \
      for (int n_ = 0; n_ < 4; ++n_)                                          \
        bq[n_] = *(const bf16x8*)(Br_ + boff + n_ * 1024);                    \
    }                                                                         \
    _Pragma("unroll")                                                         \
    for (int j_ = 0; j_ < 4; ++j_)                                            \
      af_[j_] = *(const bf16x8*)(Ar_ + aoff + ((fh) * 4 + j_) * 1024);        \
    STAGE_STMT;                                                               \
    __builtin_amdgcn_s_barrier();                                             \
    asm volatile("s_waitcnt lgkmcnt(0)" ::: "memory");                        \
    __builtin_amdgcn_sched_barrier(0);                                        \
    __builtin_amdgcn_s_setprio(1);                                            \
    _Pragma("unroll")                                                         \
    for (int j_ = 0; j_ < 4; ++j_)                                            \
      _Pragma("unroll")                                                       \
      for (int n_ = 0; n_ < 4; ++n_)                                          \
        acc[(fh) * 4 + j_][n_] = __builtin_amdgcn_mfma_f32_16x16x32_bf16(     \
            af_[j_], bq[n_], acc[(fh) * 4 + j_][n_], 0, 0, 0);                \
    __builtin_amdgcn_s_setprio(0);                                            \
    ENDM();                                                                   \
  } while (0)

  // prologue: stage tile 0 fully (8 loads, order A0,B0,A1,B1); wait oldest 4.
  STAGE_A(0, 0); STAGE_B(0, 0); STAGE_A(0, 1); STAGE_B(0, 1);
  END_V4();

  // main loop: 31 iterations, tiles 0..61; tile 62 staged by i=30 phases 5-8.
  for (int i = 0; i < 31; ++i) {
    const int T1 = 2 * i + 1, T2 = 2 * i + 2;
    PH(0, 0, 0, STAGE_A(T1, 0), END_P);   // p1
    PH(0, 0, 1, STAGE_B(T1, 0), END_V4);  // p2: tile2i A1,B1 land
    PH(0, 1, 0, STAGE_A(T1, 1), END_P);   // p3
    PH(0, 1, 1, STAGE_B(T1, 1), END_V4);  // p4: tile2i+1 A0,B0 land
    PH(1, 0, 0, STAGE_A(T2, 0), END_P);   // p5
    PH(1, 0, 1, STAGE_B(T2, 0), END_V4);  // p6: tile2i+1 A1,B1 land
    PH(1, 1, 0, STAGE_A(T2, 1), END_P);   // p7
    PH(1, 1, 1, STAGE_B(T2, 1), END_V4);  // p8: tile2i+2 A0,B0 land
  }
  // final iteration (tiles 62, 63): stage only tile 63; drain 4 -> 4 -> 0.
  PH(0, 0, 0, STAGE_A(63, 0), END_P);
  PH(0, 0, 1, STAGE_B(63, 0), END_V4);    // tile62 A1,B1 land
  PH(0, 1, 0, STAGE_A(63, 1), END_P);
  PH(0, 1, 1, STAGE_B(63, 1), END_V4);    // tile63 A0,B0 land
  PH(1, 0, 0, ((void)0), END_P);
  PH(1, 0, 1, ((void)0), END_V0);         // tile63 A1,B1 land
  PH(1, 1, 0, ((void)0), END_P);
  PH(1, 1, 1, ((void)0), END_P);

#undef PH
#undef STAGE_A
#undef STAGE_B
#undef END_P
#undef END_V4
#undef END_V0

  // epilogue: C/D layout col=lane&15, row=(lane>>4)*4+reg (m89/m91-verified)
  const int cr4 = (lane >> 4) * 4;
#pragma unroll
  for (int ni = 0; ni < 4; ++ni) {
    const int col = n0 + wn + ni * 16 + lr;
    const float bv = bias[col];
#pragma unroll
    for (int mi = 0; mi < 8; ++mi) {
      const int row = m0 + wm + mi * 16 + cr4;
#pragma unroll
      for (int jj = 0; jj < 4; ++jj)
        C[(size_t)(row + jj) * NOUT + col] = acc[mi][ni][jj] + bv;
    }
  }
}

// ---------------------------------------------------------------------------
extern "C" void kernel_launch(void* const* d_in, const int* in_sizes, int n_in,
                              void* d_out, int out_size, void* d_ws, size_t ws_size,
                              hipStream_t stream) {
  const float* x    = (const float*)d_in[0];
  const float* Wqkv = (const float*)d_in[1];
  const float* bias = (const float*)d_in[2];
  const float* Aq   = (const float*)d_in[3];
  const float* Bq   = (const float*)d_in[4];
  const float* Bk   = (const float*)d_in[5];
  const float* Bv   = (const float*)d_in[6];
  float* out = (float*)d_out;

  unsigned short* xb = (unsigned short*)d_ws;                 // 128 MB
  unsigned short* wb = xb + (size_t)S_TOK * DIN;              // 48 MB

  cvt_f32_bf16<<<2048, 256, 0, stream>>>(x, xb, S_TOK * DIN / 4);

  dim3 g1(NOUT / 64, DIN / 128);
  prep_weff<<<g1, 256, 0, stream>>>(Wqkv, Aq, Bq, Bk, Bv, wb);

  gemm_bt_bias<<<1536, 512, 0, stream>>>(xb, wb, bias, out);
}

// Round 4
// 935.285 us; speedup vs baseline: 1.3268x; 1.0868x over previous
//
#include <hip/hip_runtime.h>
#include <hip/hip_bf16.h>
#include <stdint.h>

// Problem constants (QKVParallelLinearWithLoRA)
#define S_TOK 16384
#define DIN   4096
#define OUTQ  4096
#define OUTKV 1024
#define NOUT  6144   // OUTQ + 2*OUTKV
#define LRANK 64

typedef __attribute__((ext_vector_type(8))) short bf16x8;           // 8 bf16 = 4 VGPR
typedef __attribute__((ext_vector_type(4))) float f32x4;            // MFMA acc frag
typedef __attribute__((ext_vector_type(4))) unsigned short u16x4;   // 4 bf16 store

static __device__ __forceinline__ unsigned short f2bf(float f) {
  uint32_t u = __float_as_uint(f);
  u += 0x7FFFu + ((u >> 16) & 1u);
  return (unsigned short)(u >> 16);
}

static __device__ __forceinline__ void gload_lds16(const void* g, void* l) {
  __builtin_amdgcn_global_load_lds((const __attribute__((address_space(1))) void*)g,
                                   (__attribute__((address_space(3))) void*)l,
                                   16, 0, 0);
}

// ---------------------------------------------------------------------------
// Kernel 1: x fp32 -> bf16
// ---------------------------------------------------------------------------
__global__ __launch_bounds__(256) void cvt_f32_bf16(const float* __restrict__ in,
                                                    unsigned short* __restrict__ out,
                                                    int n4) {
  int i = blockIdx.x * blockDim.x + threadIdx.x;
  const int stride = gridDim.x * blockDim.x;
  const float4* in4 = (const float4*)in;
  for (; i < n4; i += stride) {
    float4 v = in4[i];
    u16x4 o;
    o.x = f2bf(v.x); o.y = f2bf(v.y); o.z = f2bf(v.z); o.w = f2bf(v.w);
    *(u16x4*)(out + (size_t)i * 4) = o;
  }
}

// ---------------------------------------------------------------------------
// Kernel 2: W_eff[o][d] = W[o][d] + sum_r B_seg[o'][r] * A[seg*64+r][d] -> bf16
// ---------------------------------------------------------------------------
__global__ __launch_bounds__(256) void prep_weff(const float* __restrict__ W,
                                                 const float* __restrict__ A,
                                                 const float* __restrict__ Bq,
                                                 const float* __restrict__ Bk,
                                                 const float* __restrict__ Bv,
                                                 unsigned short* __restrict__ Weff) {
  __shared__ float As_[64][128];
  __shared__ float Bs_[64][64];
  const int o0 = blockIdx.x * 64;
  const int d0 = blockIdx.y * 128;
  const int t = threadIdx.x;

  const float* Bseg; int seg, ob;
  if (o0 < OUTQ)              { seg = 0; Bseg = Bq; ob = o0; }
  else if (o0 < OUTQ + OUTKV) { seg = 1; Bseg = Bk; ob = o0 - OUTQ; }
  else                        { seg = 2; Bseg = Bv; ob = o0 - OUTQ - OUTKV; }

  {
    const float4* src = (const float4*)(Bseg + (size_t)ob * LRANK);
    float4* dst = (float4*)&Bs_[0][0];
    for (int i = t; i < 64 * 64 / 4; i += 256) dst[i] = src[i];
  }
  for (int i = t; i < 64 * 32; i += 256) {
    int r = i >> 5, c4 = i & 31;
    *(float4*)&As_[r][c4 * 4] =
        *(const float4*)(A + (size_t)(seg * 64 + r) * DIN + d0 + c4 * 4);
  }
  __syncthreads();

  const int tx = t & 31;
  const int tg = t >> 5;
  for (int oi = tg * 8; oi < tg * 8 + 8; ++oi) {
    const int o = o0 + oi;
    float4 acc = *(const float4*)(W + (size_t)o * DIN + d0 + tx * 4);
#pragma unroll 8
    for (int r = 0; r < 64; ++r) {
      const float b = Bs_[oi][r];
      const float4 a = *(const float4*)&As_[r][tx * 4];
      acc.x += b * a.x; acc.y += b * a.y; acc.z += b * a.z; acc.w += b * a.w;
    }
    u16x4 ov;
    ov.x = f2bf(acc.x); ov.y = f2bf(acc.y); ov.z = f2bf(acc.z); ov.w = f2bf(acc.w);
    *(u16x4*)(Weff + (size_t)o * DIN + d0 + tx * 4) = ov;
  }
}

// ---------------------------------------------------------------------------
// Kernel 3: 256x256 GEMM, BK=64, 8-phase schedule (T1+T2+T3+T4+T5).
//   C[m,n] = sum_k Xb[m,k]*Wb[n,k] + bias[n]
// Identical schedule to R3 (which measured MfmaUtil 43%, 0 bank conflicts)
// except: (a) 2-D co-residency block swizzle -- each XCD's 32 concurrent
// blocks form an 8mt x 4nt rectangle so per-K-step staging working set is
// 8 A-slices + 4 B-slices = 384KB (L2-fit; each L3 fetch amortized 4-8x),
// attacking the ~7.1 TB/s staging-path saturation that R3's phase-time
// arithmetic identified (1406 cyc/phase observed vs 1413 predicted if
// staging-BW-bound); (b) sched_barrier(0) removed (not in m201 template).
// ---------------------------------------------------------------------------
__global__ __launch_bounds__(512, 1) void gemm_bt_bias(const unsigned short* __restrict__ Xb,
                                                       const unsigned short* __restrict__ Wb,
                                                       const float* __restrict__ bias,
                                                       float* __restrict__ C) {
  __shared__ unsigned short Alds[32768];  // [buf][kh][256 rows][32 k] = 4x16KB
  __shared__ unsigned short Blds[32768];

  // 2-D co-residency swizzle: block b -> XCD b%8 (HW round-robin), local slot
  // l=b/8 in rough dispatch order. XCD x owns mt-band [8x, 8x+8); its 32
  // concurrent slots tile an 8mt x 4nt rectangle; generations g sweep nt.
  const int bid = blockIdx.x;
  const int x = bid & 7;                  // XCD
  const int l = bid >> 3;                 // 0..191 within XCD
  const int g = l >> 5;                   // generation 0..5
  const int i5 = l & 31;                  // slot in 8x4 rectangle
  const int mt = x * 8 + (i5 & 7);
  const int nt = g * 4 + (i5 >> 3);
  const int m0 = mt * 256;
  const int n0 = nt * 256;

  const int t = threadIdx.x;
  const int lane = t & 63;
  const int w = t >> 6;
  const int wm = (w >> 2) * 128;          // 2 waves in M
  const int wn = (w & 3) * 64;            // 4 waves in N

  // ---- staging: thread t covers region row trow (+128 for 2nd gload),
  // phys 16B-slot t&3; logical k-slot = (t&3)^((trow>>1)&3) (inverse swizzle
  // applied to global source; LDS dest stays linear).
  const int trow = t >> 2;
  const int ksl = (t & 3) ^ ((trow >> 1) & 3);
  const size_t gA0 = (size_t)(m0 + trow) * DIN + ksl * 8;
  const size_t gA1 = (size_t)(m0 + 128 + trow) * DIN + ksl * 8;
  const size_t gB0 = (size_t)(n0 + trow) * DIN + ksl * 8;
  const size_t gB1 = (size_t)(n0 + 128 + trow) * DIN + ksl * 8;
  const int ldst = t * 8;                 // element offset within region

#define STAGE_A(T, kh) do {                                                   \
    const int rb_ = (((T) & 1) * 2 + (kh)) * 8192;                            \
    const size_t ko_ = (size_t)((T) * 64 + (kh) * 32);                        \
    gload_lds16(Xb + gA0 + ko_, &Alds[rb_ + ldst]);                           \
    gload_lds16(Xb + gA1 + ko_, &Alds[rb_ + 4096 + ldst]);                    \
  } while (0)
#define STAGE_B(T, kh) do {                                                   \
    const int rb_ = (((T) & 1) * 2 + (kh)) * 8192;                            \
    const size_t ko_ = (size_t)((T) * 64 + (kh) * 32);                        \
    gload_lds16(Wb + gB0 + ko_, &Blds[rb_ + ldst]);                           \
    gload_lds16(Wb + gB1 + ko_, &Blds[rb_ + 4096 + ldst]);                    \
  } while (0)

  // ---- fragment read offsets (bytes within region): row = base + lr,
  // 16B at (lane>>4)*16, swizzle-xor reduces to per-lane constant.
  const int lr = lane & 15;
  const int ks16 = (lane >> 4) * 16;
  const int fxor = ((lr >> 1) & 3) << 4;
  const int aoff = ((wm + lr) * 64 + ks16) ^ fxor;
  const int boff = ((wn + lr) * 64 + ks16) ^ fxor;

  f32x4 acc[8][4];
#pragma unroll
  for (int i = 0; i < 8; ++i)
#pragma unroll
    for (int j = 0; j < 4; ++j)
      acc[i][j] = f32x4{0.f, 0.f, 0.f, 0.f};
  bf16x8 bq[4];

#define END_P()  __builtin_amdgcn_s_barrier()
#define END_V4() do { asm volatile("s_waitcnt vmcnt(4)" ::: "memory");        \
                      __builtin_amdgcn_s_barrier(); } while (0)
#define END_V0() do { asm volatile("s_waitcnt vmcnt(0)" ::: "memory");        \
                      __builtin_amdgcn_s_barrier(); } while (0)

  // PH(buf, ks, fh, STAGE_STMT, ENDM): one phase.
#define PH(buf, ks, fh, STAGE_STMT, ENDM) do {                                \
    const char* Ar_ = (const char*)&Alds[((buf) * 2 + (ks)) * 8192];          \
    const char* Br_ = (const char*)&Blds[((buf) * 2 + (ks)) * 8192];          \
    bf16x8 af_[4];                                                            \
    if ((fh) == 0) {                                                          \
      _Pragma("unroll")                                                       \
      for (int n_ = 0; n_ < 4; ++n_)                                          \
        bq[n_] = *(const bf16x8*)(Br_ + boff + n_ * 1024);                    \
    }                                                                         \
    _Pragma("unroll")                                                         \
    for (int j_ = 0; j_ < 4; ++j_)                                            \
      af_[j_] = *(const bf16x8*)(Ar_ + aoff + ((fh) * 4 + j_) * 1024);        \
    STAGE_STMT;                                                               \
    __builtin_amdgcn_s_barrier();                                             \
    asm volatile("s_waitcnt lgkmcnt(0)" ::: "memory");                        \
    __builtin_amdgcn_s_setprio(1);                                            \
    _Pragma("unroll")                                                         \
    for (int j_ = 0; j_ < 4; ++j_)                                            \
      _Pragma("unroll")                                                       \
      for (int n_ = 0; n_ < 4; ++n_)                                          \
        acc[(fh) * 4 + j_][n_] = __builtin_amdgcn_mfma_f32_16x16x32_bf16(     \
            af_[j_], bq[n_], acc[(fh) * 4 + j_][n_], 0, 0, 0);                \
    __builtin_amdgcn_s_setprio(0);                                            \
    ENDM();                                                                   \
  } while (0)

  // prologue: stage tile 0 fully (8 loads, order A0,B0,A1,B1); wait oldest 4.
  STAGE_A(0, 0); STAGE_B(0, 0); STAGE_A(0, 1); STAGE_B(0, 1);
  END_V4();

  // main loop: 31 iterations, tiles 0..61; tile 62 staged by i=30 phases 5-8.
  for (int i = 0; i < 31; ++i) {
    const int T1 = 2 * i + 1, T2 = 2 * i + 2;
    PH(0, 0, 0, STAGE_A(T1, 0), END_P);   // p1
    PH(0, 0, 1, STAGE_B(T1, 0), END_V4);  // p2: tile2i A1,B1 land
    PH(0, 1, 0, STAGE_A(T1, 1), END_P);   // p3
    PH(0, 1, 1, STAGE_B(T1, 1), END_V4);  // p4: tile2i+1 A0,B0 land
    PH(1, 0, 0, STAGE_A(T2, 0), END_P);   // p5
    PH(1, 0, 1, STAGE_B(T2, 0), END_V4);  // p6: tile2i+1 A1,B1 land
    PH(1, 1, 0, STAGE_A(T2, 1), END_P);   // p7
    PH(1, 1, 1, STAGE_B(T2, 1), END_V4);  // p8: tile2i+2 A0,B0 land
  }
  // final iteration (tiles 62, 63): stage only tile 63; drain 4 -> 4 -> 0.
  PH(0, 0, 0, STAGE_A(63, 0), END_P);
  PH(0, 0, 1, STAGE_B(63, 0), END_V4);    // tile62 A1,B1 land
  PH(0, 1, 0, STAGE_A(63, 1), END_P);
  PH(0, 1, 1, STAGE_B(63, 1), END_V4);    // tile63 A0,B0 land
  PH(1, 0, 0, ((void)0), END_P);
  PH(1, 0, 1, ((void)0), END_V0);         // tile63 A1,B1 land
  PH(1, 1, 0, ((void)0), END_P);
  PH(1, 1, 1, ((void)0), END_P);

#undef PH
#undef STAGE_A
#undef STAGE_B
#undef END_P
#undef END_V4
#undef END_V0

  // epilogue: C/D layout col=lane&15, row=(lane>>4)*4+reg (m89/m91-verified)
  const int cr4 = (lane >> 4) * 4;
#pragma unroll
  for (int ni = 0; ni < 4; ++ni) {
    const int col = n0 + wn + ni * 16 + lr;
    const float bv = bias[col];
#pragma unroll
    for (int mi = 0; mi < 8; ++mi) {
      const int row = m0 + wm + mi * 16 + cr4;
#pragma unroll
      for (int jj = 0; jj < 4; ++jj)
        C[(size_t)(row + jj) * NOUT + col] = acc[mi][ni][jj] + bv;
    }
  }
}

// ---------------------------------------------------------------------------
extern "C" void kernel_launch(void* const* d_in, const int* in_sizes, int n_in,
                              void* d_out, int out_size, void* d_ws, size_t ws_size,
                              hipStream_t stream) {
  const float* x    = (const float*)d_in[0];
  const float* Wqkv = (const float*)d_in[1];
  const float* bias = (const float*)d_in[2];
  const float* Aq   = (const float*)d_in[3];
  const float* Bq   = (const float*)d_in[4];
  const float* Bk   = (const float*)d_in[5];
  const float* Bv   = (const float*)d_in[6];
  float* out = (float*)d_out;

  unsigned short* xb = (unsigned short*)d_ws;                 // 128 MB
  unsigned short* wb = xb + (size_t)S_TOK * DIN;              // 48 MB

  cvt_f32_bf16<<<2048, 256, 0, stream>>>(x, xb, S_TOK * DIN / 4);

  dim3 g1(NOUT / 64, DIN / 128);
  prep_weff<<<g1, 256, 0, stream>>>(Wqkv, Aq, Bq, Bk, Bv, wb);

  gemm_bt_bias<<<1536, 512, 0, stream>>>(xb, wb, bias, out);
}